// Round 2
// baseline (185.779 us; speedup 1.0000x reference)
//
#include <hip/hip_runtime.h>

// ---------------------------------------------------------------------------
// Self-attention: out = softmax((xWq)(xWk)^T / sqrt(64)) (xWv)
// B=4, N=4096, Din=128, Dout=64.
//   k1 qkv_kernel : x@W via 3-pass bf16 MFMA -> Qhi/Qlo (pre-scaled), Khi/Klo,
//                   Vt [b][d][n] bf16. Epilogue via LDS transpose, coalesced.
//   k2 attn_kernel: flash attention, 1 wave / 64 q, 32x32x16 bf16 MFMA,
//                   S^T = K·Q^T (3-pass), online softmax base-2, P·V bf16.
//                   8 key-segments (512 keys each) -> 2048 waves = 2/SIMD.
//                   V loaded direct-from-global in B-frag layout (prefetched).
//   k3 merge_kernel: combine 8 segment partials (bf16 O partials).
// ---------------------------------------------------------------------------

typedef __attribute__((ext_vector_type(8))) short bf16x8;
typedef __attribute__((ext_vector_type(16))) float f32x16;
typedef unsigned short us;

__device__ __forceinline__ us f2bf(float f) {               // RTNE fp32->bf16
  unsigned u = __builtin_bit_cast(unsigned, f);
  u += 0x7FFFu + ((u >> 16) & 1u);
  return (us)(u >> 16);
}
__device__ __forceinline__ float bf2f(us h) {
  unsigned u = ((unsigned)h) << 16;
  return __builtin_bit_cast(float, u);
}
__device__ __forceinline__ f32x16 mfma(bf16x8 a, bf16x8 b, f32x16 c) {
  return __builtin_amdgcn_mfma_f32_32x32x16_bf16(a, b, c, 0, 0, 0);
}
__device__ __forceinline__ unsigned pk2(float a, float b) {
  return (unsigned)f2bf(a) | ((unsigned)f2bf(b) << 16);
}

// ---------------------------------------------------------------------------
// Kernel 1: QKV projection. 256 blocks x 256 thr. block = 128 rows x 96 cols.
// Epilogue: acc -> LDS tile (hi|lo packed uint, pitch 101) -> coalesced
// dwordx4 stores for Q/K (row-major) and Vt (transposed, packed along n).
// ---------------------------------------------------------------------------
#define WP 136  // W tile pitch (shorts)
#define TP 101  // transpose tile pitch (uints): 5*row+col banks, col reads 4-way max

__global__ __launch_bounds__(256, 1) void qkv_kernel(
    const float* __restrict__ x, const float* __restrict__ w,
    us* __restrict__ Qhi, us* __restrict__ Qlo,
    us* __restrict__ Khi, us* __restrict__ Klo, us* __restrict__ Vt)
{
  __shared__ union {
    us wtile[2][96 * WP];        // 52,224 B
    unsigned ttile[128 * TP];    // 51,712 B
  } sm;
  us* whi = sm.wtile[0];
  us* wlo = sm.wtile[1];
  const int t = threadIdx.x;
  const int rb = blockIdx.x >> 1, ch = blockIdx.x & 1;  // rowblock, col-half

  // stage W: read all 24576 fp32, keep our 96 cols, write transposed hi/lo
  for (int i = t; i < 24576; i += 256) {
    int p = i >> 13, rem = i & 8191;
    int d = rem >> 6, e = rem & 63;
    int cl = ((p << 6) + e) - ch * 96;
    if ((unsigned)cl < 96u) {
      float v = w[i];
      us hi = f2bf(v);
      whi[cl * WP + d] = hi;
      wlo[cl * WP + d] = f2bf(v - bf2f(hi));
    }
  }
  __syncthreads();

  const int wid = t >> 6, lane = t & 63;
  const int l31 = lane & 31, h = lane >> 5;
  const int rbase = rb * 128 + wid * 32;
  const float* xrow = x + (size_t)(rbase + l31) * 128;

  f32x16 acc[3] = {};
  #pragma unroll
  for (int ks = 0; ks < 8; ++ks) {           // K = 128 = 8 * 16
    const int d0 = ks * 16 + h * 8;
    const float4 xa = *(const float4*)(xrow + d0);
    const float4 xb = *(const float4*)(xrow + d0 + 4);
    const float xv[8] = {xa.x, xa.y, xa.z, xa.w, xb.x, xb.y, xb.z, xb.w};
    bf16x8 ah, al;
    #pragma unroll
    for (int j = 0; j < 8; ++j) {
      us hi = f2bf(xv[j]);
      ah[j] = (short)hi;
      al[j] = (short)f2bf(xv[j] - bf2f(hi));
    }
    #pragma unroll
    for (int nt = 0; nt < 3; ++nt) {
      bf16x8 bh = *(const bf16x8*)(&whi[(l31 + 32 * nt) * WP + d0]);
      bf16x8 bl = *(const bf16x8*)(&wlo[(l31 + 32 * nt) * WP + d0]);
      acc[nt] = mfma(ah, bh, acc[nt]);
      acc[nt] = mfma(al, bh, acc[nt]);
      acc[nt] = mfma(ah, bl, acc[nt]);
    }
  }
  __syncthreads();  // done reading W; tile aliases it

  // write packed hi|lo into transpose tile. C layout: row=(r&3)+8*(r>>2)+4h
  const float cq = 0.18033688011112042f;  // 0.125 * log2(e) folded into Q
  #pragma unroll
  for (int nt = 0; nt < 3; ++nt) {
    const bool isQ = (ch == 0) && (nt < 2);   // global cols 0..63
    const int col = 32 * nt + l31;
    #pragma unroll
    for (int r = 0; r < 16; ++r) {
      const int rl = (r & 3) + 8 * (r >> 2) + 4 * h;
      float v = acc[nt][r];
      if (isQ) v *= cq;
      us hi = f2bf(v);
      us lo = f2bf(v - bf2f(hi));
      sm.ttile[(wid * 32 + rl) * TP + col] = (unsigned)hi | ((unsigned)lo << 16);
    }
  }
  __syncthreads();

  // coalesced store phase
  const int row = t >> 1;
  const int grow = rb * 128 + row;
  if (ch == 0) {
    {  // Q: local cols 0..63
      const int cb = (t & 1) * 32;
      unsigned hw[16], lw[16];
      #pragma unroll
      for (int j = 0; j < 16; ++j) {
        unsigned a = sm.ttile[row * TP + cb + 2 * j];
        unsigned bv = sm.ttile[row * TP + cb + 2 * j + 1];
        hw[j] = (a & 0xffffu) | (bv << 16);
        lw[j] = (a >> 16) | (bv & 0xffff0000u);
      }
      #pragma unroll
      for (int j = 0; j < 4; ++j) {
        uint4 hv = {hw[4 * j], hw[4 * j + 1], hw[4 * j + 2], hw[4 * j + 3]};
        uint4 lv = {lw[4 * j], lw[4 * j + 1], lw[4 * j + 2], lw[4 * j + 3]};
        *(uint4*)(Qhi + (size_t)grow * 64 + cb + 8 * j) = hv;
        *(uint4*)(Qlo + (size_t)grow * 64 + cb + 8 * j) = lv;
      }
    }
    {  // K: local cols 64..95 -> e 0..31
      const int cs = (t & 1) * 16;
      unsigned hw[8], lw[8];
      #pragma unroll
      for (int j = 0; j < 8; ++j) {
        unsigned a = sm.ttile[row * TP + 64 + cs + 2 * j];
        unsigned bv = sm.ttile[row * TP + 64 + cs + 2 * j + 1];
        hw[j] = (a & 0xffffu) | (bv << 16);
        lw[j] = (a >> 16) | (bv & 0xffff0000u);
      }
      #pragma unroll
      for (int j = 0; j < 2; ++j) {
        uint4 hv = {hw[4 * j], hw[4 * j + 1], hw[4 * j + 2], hw[4 * j + 3]};
        uint4 lv = {lw[4 * j], lw[4 * j + 1], lw[4 * j + 2], lw[4 * j + 3]};
        *(uint4*)(Khi + (size_t)grow * 64 + cs + 8 * j) = hv;
        *(uint4*)(Klo + (size_t)grow * 64 + cs + 8 * j) = lv;
      }
    }
  } else {
    {  // K: local cols 0..31 -> e 32..63
      const int cs = (t & 1) * 16;
      unsigned hw[8], lw[8];
      #pragma unroll
      for (int j = 0; j < 8; ++j) {
        unsigned a = sm.ttile[row * TP + cs + 2 * j];
        unsigned bv = sm.ttile[row * TP + cs + 2 * j + 1];
        hw[j] = (a & 0xffffu) | (bv << 16);
        lw[j] = (a >> 16) | (bv & 0xffff0000u);
      }
      #pragma unroll
      for (int j = 0; j < 2; ++j) {
        uint4 hv = {hw[4 * j], hw[4 * j + 1], hw[4 * j + 2], hw[4 * j + 3]};
        uint4 lv = {lw[4 * j], lw[4 * j + 1], lw[4 * j + 2], lw[4 * j + 3]};
        *(uint4*)(Khi + (size_t)grow * 64 + 32 + cs + 8 * j) = hv;
        *(uint4*)(Klo + (size_t)grow * 64 + 32 + cs + 8 * j) = lv;
      }
    }
    {  // V: local cols 32..95 -> Vt[b][e][n], hi-plane only, packed along n
      const int bb = (rb * 128) >> 12;
      const int nb = (rb * 128) & 4095;
      #pragma unroll
      for (int i2 = 0; i2 < 4; ++i2) {
        const int c = t + 256 * i2;        // 1024 chunks of 8 n
        const int e = c >> 4, nc = c & 15;
        unsigned p[4];
        #pragma unroll
        for (int j = 0; j < 4; ++j) {
          unsigned a = sm.ttile[(nc * 8 + 2 * j) * TP + 32 + e];
          unsigned bv = sm.ttile[(nc * 8 + 2 * j + 1) * TP + 32 + e];
          p[j] = (a & 0xffffu) | (bv << 16);
        }
        uint4 pv = {p[0], p[1], p[2], p[3]};
        *(uint4*)(Vt + ((size_t)(bb * 64 + e) << 12) + nb + nc * 8) = pv;
      }
    }
  }
}

// ---------------------------------------------------------------------------
// Kernel 2: flash attention partials. grid 2048 (256 q-waves x 8 key-segs),
// 64 threads (1 wave). Each wave: 64 queries x 512 keys (8 iters of 64).
// buf0: Khi tile then P (aliased). buf1: Klo tile. V read direct from global
// in B-frag layout (prefetched at iter top, consumed at PV). Single wave per
// block => no __syncthreads (per-wave DS ops are in-order).
// ---------------------------------------------------------------------------
#define KP 72  // LDS pitch (shorts): 144B rows -> frag b128 reads conflict-free

__global__ __launch_bounds__(64, 2) void attn_kernel(
    const us* __restrict__ Qhi, const us* __restrict__ Qlo,
    const us* __restrict__ Khi, const us* __restrict__ Klo,
    const us* __restrict__ Vt,
    us* __restrict__ Opart, float* __restrict__ Mpart,
    float* __restrict__ Lpart)
{
  __shared__ us buf0[64 * KP];
  __shared__ us buf1[64 * KP];
  __shared__ float alds[64];

  // XCD-aware map: XCD x serves batch x>>1 -> per-XCD K/V set fits its L2
  const int bx = blockIdx.x;
  const int xc = bx & 7, jj = bx >> 3;
  const int b = xc >> 1;
  const int idx = (xc & 1) + 2 * jj;        // 0..511
  const int seg = idx & 7, qblk = idx >> 3; // seg 0..7, qblk 0..63
  const int qw = b * 64 + qblk;             // 0..255
  const int lane = threadIdx.x;
  const int l31 = lane & 31, h = lane >> 5;

  // Q fragments (persistent): B-frag layout n=l31(+32qt), k=16*ks+8*h+j
  bf16x8 qh[2][4], ql[2][4];
  #pragma unroll
  for (int qt = 0; qt < 2; ++qt) {
    const size_t rg = (size_t)(b * 4096 + qblk * 64 + l31 + 32 * qt) * 64;
    #pragma unroll
    for (int ks = 0; ks < 4; ++ks) {
      qh[qt][ks] = *(const bf16x8*)(Qhi + rg + ks * 16 + h * 8);
      ql[qt][ks] = *(const bf16x8*)(Qlo + rg + ks * 16 + h * 8);
    }
  }
  const size_t kbase = (size_t)b * 262144;  // b*4096*64
  const size_t vbase = (size_t)b * 262144;  // b*64*4096

  f32x16 o[2][2] = {};
  float mrun[2] = {-__builtin_inff(), -__builtin_inff()};
  float lrun[2] = {0.f, 0.f};

  for (int it = 0; it < 8; ++it) {
    const int key0 = seg * 512 + it * 64;

    // V B-frags direct from global (issued first; consumed at PV -> latency
    // hidden behind K-stage + S + softmax)
    bf16x8 vb[2][4];
    #pragma unroll
    for (int dt = 0; dt < 2; ++dt) {
      #pragma unroll
      for (int ks = 0; ks < 4; ++ks) {
        vb[dt][ks] = *(const bf16x8*)(Vt + vbase +
                                      (size_t)(l31 + 32 * dt) * 4096 + key0 +
                                      ks * 16 + h * 8);
      }
    }

    // stage Khi->buf0, Klo->buf1
    #pragma unroll
    for (int i = 0; i < 8; ++i) {
      const int cid = i * 64 + lane;
      const size_t off = kbase + (size_t)(key0 + (cid >> 3)) * 64 + (cid & 7) * 8;
      bf16x8 a = *(const bf16x8*)(Khi + off);
      bf16x8 c = *(const bf16x8*)(Klo + off);
      const int loff = (cid >> 3) * KP + (cid & 7) * 8;
      *(bf16x8*)(&buf0[loff]) = a;
      *(bf16x8*)(&buf1[loff]) = c;
    }

    // S^T = K_tile · Q'^T  (3-pass hi/lo)
    f32x16 s[2][2] = {};
    #pragma unroll
    for (int m = 0; m < 2; ++m) {
      #pragma unroll
      for (int ks = 0; ks < 4; ++ks) {
        const int off = (32 * m + l31) * KP + ks * 16 + h * 8;
        bf16x8 ah = *(const bf16x8*)(&buf0[off]);
        bf16x8 al = *(const bf16x8*)(&buf1[off]);
        #pragma unroll
        for (int qt = 0; qt < 2; ++qt) {
          s[m][qt] = mfma(ah, qh[qt][ks], s[m][qt]);
          s[m][qt] = mfma(al, qh[qt][ks], s[m][qt]);
          s[m][qt] = mfma(ah, ql[qt][ks], s[m][qt]);
        }
      }
    }

    // online softmax (base-2; scale pre-folded into Q). Lane owns q=32qt+l31,
    // holds 32 of its 64 key-scores; partner lane (xor 32) holds the rest.
    float alpha[2];
    #pragma unroll
    for (int qt = 0; qt < 2; ++qt) {
      float vm = -__builtin_inff();
      #pragma unroll
      for (int r = 0; r < 16; ++r)
        vm = fmaxf(vm, fmaxf(s[0][qt][r], s[1][qt][r]));
      vm = fmaxf(vm, __shfl_xor(vm, 32));
      const float mnew = fmaxf(mrun[qt], vm);
      alpha[qt] = exp2f(mrun[qt] - mnew);
      float sum = 0.f;
      #pragma unroll
      for (int r = 0; r < 16; ++r) {
        const float p0 = exp2f(s[0][qt][r] - mnew);
        const float p1 = exp2f(s[1][qt][r] - mnew);
        s[0][qt][r] = p0;
        s[1][qt][r] = p1;
        sum += p0 + p1;
      }
      sum += __shfl_xor(sum, 32);
      lrun[qt] = lrun[qt] * alpha[qt] + sum;
      mrun[qt] = mnew;
    }

    // write P into buf0 (over Khi; S-phase reads done): row q=32qt+l31
    #pragma unroll
    for (int qt = 0; qt < 2; ++qt) {
      #pragma unroll
      for (int m = 0; m < 2; ++m) {
        #pragma unroll
        for (int g = 0; g < 4; ++g) {
          uint2 u;
          u.x = pk2(s[m][qt][4 * g + 0], s[m][qt][4 * g + 1]);
          u.y = pk2(s[m][qt][4 * g + 2], s[m][qt][4 * g + 3]);
          *(uint2*)(&buf0[(l31 + 32 * qt) * KP + 32 * m + 8 * g + 4 * h]) = u;
        }
      }
    }

    // rescale O by alpha (skip when all-ones; LDS broadcast to C-layout rows)
    if (__any((alpha[0] != 1.f) || (alpha[1] != 1.f))) {
      alds[lane] = h ? alpha[1] : alpha[0];
      #pragma unroll
      for (int qt = 0; qt < 2; ++qt) {
        #pragma unroll
        for (int g = 0; g < 4; ++g) {
          const float4 af = *(const float4*)(&alds[32 * qt + 8 * g + 4 * h]);
          #pragma unroll
          for (int rr = 0; rr < 4; ++rr) {
            const int r = 4 * g + rr;
            const float a = (rr == 0) ? af.x : (rr == 1) ? af.y
                           : (rr == 2) ? af.z : af.w;
            o[qt][0][r] *= a;
            o[qt][1][r] *= a;
          }
        }
      }
    }

    // PV: O[q][d] += P[q][key] * V[key][d]; V frags direct from regs
    #pragma unroll
    for (int ks = 0; ks < 4; ++ks) {
      const int fo = ks * 16 + h * 8;
      bf16x8 p0 = *(const bf16x8*)(&buf0[l31 * KP + fo]);
      bf16x8 p1 = *(const bf16x8*)(&buf0[(l31 + 32) * KP + fo]);
      o[0][0] = mfma(p0, vb[0][ks], o[0][0]);
      o[0][1] = mfma(p0, vb[1][ks], o[0][1]);
      o[1][0] = mfma(p1, vb[0][ks], o[1][0]);
      o[1][1] = mfma(p1, vb[1][ks], o[1][1]);
    }
  }

  // store partials (unnormalized O in bf16 + per-q m,l)
  const size_t pb = (size_t)(qw * 8 + seg);
  us* op = Opart + pb * 4096;
  #pragma unroll
  for (int qt = 0; qt < 2; ++qt) {
    #pragma unroll
    for (int dt = 0; dt < 2; ++dt) {
      #pragma unroll
      for (int r = 0; r < 16; ++r) {
        const int q_l = 32 * qt + (r & 3) + 8 * (r >> 2) + 4 * h;
        op[q_l * 64 + l31 + 32 * dt] = f2bf(o[qt][dt][r]);
      }
    }
  }
  Mpart[pb * 64 + lane] = h ? mrun[1] : mrun[0];
  Lpart[pb * 64 + lane] = h ? lrun[1] : lrun[0];
}

// ---------------------------------------------------------------------------
// Kernel 3: merge 8 key-segment partials (bf16). 131072 threads, 8 d each.
// ---------------------------------------------------------------------------
__global__ __launch_bounds__(256, 1) void merge_kernel(
    const us* __restrict__ Opart, const float* __restrict__ Mpart,
    const float* __restrict__ Lpart, float* __restrict__ out)
{
  const int tg = blockIdx.x * 256 + threadIdx.x;
  const int q = tg >> 3, dc = (tg & 7) * 8;
  const int qw = q >> 6, ql = q & 63;
  const int base = qw * 8;
  float m[8];
  float M = -__builtin_inff();
  #pragma unroll
  for (int s = 0; s < 8; ++s) {
    m[s] = Mpart[(size_t)(base + s) * 64 + ql];
    M = fmaxf(M, m[s]);
  }
  float acc[8] = {};
  float den = 0.f;
  #pragma unroll
  for (int s = 0; s < 8; ++s) {
    const float wgt = exp2f(m[s] - M);
    den += wgt * Lpart[(size_t)(base + s) * 64 + ql];
    const uint4 r = *(const uint4*)(Opart + (size_t)(base + s) * 4096 +
                                    ql * 64 + dc);
    const unsigned rw[4] = {r.x, r.y, r.z, r.w};
    #pragma unroll
    for (int j = 0; j < 4; ++j) {
      acc[2 * j]     += wgt * bf2f((us)(rw[j] & 0xffffu));
      acc[2 * j + 1] += wgt * bf2f((us)(rw[j] >> 16));
    }
  }
  const float inv = 1.f / den;
  float4 r0 = {acc[0] * inv, acc[1] * inv, acc[2] * inv, acc[3] * inv};
  float4 r1 = {acc[4] * inv, acc[5] * inv, acc[6] * inv, acc[7] * inv};
  *(float4*)(out + (size_t)q * 64 + dc) = r0;
  *(float4*)(out + (size_t)q * 64 + dc + 4) = r1;
}

// ---------------------------------------------------------------------------
extern "C" void kernel_launch(void* const* d_in, const int* in_sizes, int n_in,
                              void* d_out, int out_size, void* d_ws,
                              size_t ws_size, hipStream_t stream)
{
  const float* x = (const float*)d_in[0];
  const float* w = (const float*)d_in[1];
  float* out = (float*)d_out;
  char* ws = (char*)d_ws;

  const size_t T = 2097152;  // bytes per bf16 [4,4096,64] tensor
  us* Qhi = (us*)(ws + 0 * T);
  us* Qlo = (us*)(ws + 1 * T);
  us* Khi = (us*)(ws + 2 * T);
  us* Klo = (us*)(ws + 3 * T);
  us* Vt  = (us*)(ws + 4 * T);
  us* Opart = (us*)(ws + 5 * T);                             // 16,777,216 B
  float* Mpart = (float*)(ws + 5 * T + 16777216);            //    524,288 B
  float* Lpart = (float*)(ws + 5 * T + 16777216 + 524288);   //    524,288 B
  // total workspace use: ~28.3 MiB

  hipLaunchKernelGGL(qkv_kernel, dim3(256), dim3(256), 0, stream,
                     x, w, Qhi, Qlo, Khi, Klo, Vt);
  hipLaunchKernelGGL(attn_kernel, dim3(2048), dim3(64), 0, stream,
                     Qhi, Qlo, Khi, Klo, Vt, Opart, Mpart, Lpart);
  hipLaunchKernelGGL(merge_kernel, dim3(512), dim3(256), 0, stream,
                     Opart, Mpart, Lpart, out);
}

// Round 3
// 149.512 us; speedup vs baseline: 1.2426x; 1.2426x over previous
//
#include <hip/hip_runtime.h>

// ---------------------------------------------------------------------------
// Self-attention: out = softmax((xWq)(xWk)^T / sqrt(64)) (xWv)
// B=4, N=4096, Din=128, Dout=64.
//   k1 qkv_kernel : x@W via 3-pass bf16 MFMA -> Qhi/Qlo (pre-scaled), Khi/Klo,
//                   Vt [b][d][n] bf16. Epilogue via LDS transpose, coalesced.
//   k2 attn_kernel: flash attention, 256-thr blocks (4 waves share K/V tiles),
//                   each wave owns 64 q. 32x32x16 bf16 MFMA, S^T=K.Q^T 3-pass,
//                   online softmax base-2, PV bf16. 8 key-segments. Next tile
//                   register-prefetched; coalesced loads only. Opart bf16 via
//                   LDS-bounce packed dwordx4 stores (no 2B-store
//                   write-amplification — round-2 lesson).
//   k3 merge_kernel: combine 8 segment partials (bf16 O partials).
// ---------------------------------------------------------------------------

typedef __attribute__((ext_vector_type(8))) short bf16x8;
typedef __attribute__((ext_vector_type(16))) float f32x16;
typedef unsigned short us;

__device__ __forceinline__ us f2bf(float f) {               // RTNE fp32->bf16
  unsigned u = __builtin_bit_cast(unsigned, f);
  u += 0x7FFFu + ((u >> 16) & 1u);
  return (us)(u >> 16);
}
__device__ __forceinline__ float bf2f(us h) {
  unsigned u = ((unsigned)h) << 16;
  return __builtin_bit_cast(float, u);
}
__device__ __forceinline__ f32x16 mfma(bf16x8 a, bf16x8 b, f32x16 c) {
  return __builtin_amdgcn_mfma_f32_32x32x16_bf16(a, b, c, 0, 0, 0);
}
__device__ __forceinline__ unsigned pk2(float a, float b) {
  return (unsigned)f2bf(a) | ((unsigned)f2bf(b) << 16);
}
#define EXP2(x) __builtin_amdgcn_exp2f(x)

// ---------------------------------------------------------------------------
// Kernel 1: QKV projection (unchanged from round 2; passed).
// ---------------------------------------------------------------------------
#define WP 136  // W tile pitch (shorts)
#define TP 101  // transpose tile pitch (uints)

__global__ __launch_bounds__(256, 1) void qkv_kernel(
    const float* __restrict__ x, const float* __restrict__ w,
    us* __restrict__ Qhi, us* __restrict__ Qlo,
    us* __restrict__ Khi, us* __restrict__ Klo, us* __restrict__ Vt)
{
  __shared__ union {
    us wtile[2][96 * WP];
    unsigned ttile[128 * TP];
  } sm;
  us* whi = sm.wtile[0];
  us* wlo = sm.wtile[1];
  const int t = threadIdx.x;
  const int rb = blockIdx.x >> 1, ch = blockIdx.x & 1;

  for (int i = t; i < 24576; i += 256) {
    int p = i >> 13, rem = i & 8191;
    int d = rem >> 6, e = rem & 63;
    int cl = ((p << 6) + e) - ch * 96;
    if ((unsigned)cl < 96u) {
      float v = w[i];
      us hi = f2bf(v);
      whi[cl * WP + d] = hi;
      wlo[cl * WP + d] = f2bf(v - bf2f(hi));
    }
  }
  __syncthreads();

  const int wid = t >> 6, lane = t & 63;
  const int l31 = lane & 31, h = lane >> 5;
  const int rbase = rb * 128 + wid * 32;
  const float* xrow = x + (size_t)(rbase + l31) * 128;

  f32x16 acc[3] = {};
  #pragma unroll
  for (int ks = 0; ks < 8; ++ks) {
    const int d0 = ks * 16 + h * 8;
    const float4 xa = *(const float4*)(xrow + d0);
    const float4 xb = *(const float4*)(xrow + d0 + 4);
    const float xv[8] = {xa.x, xa.y, xa.z, xa.w, xb.x, xb.y, xb.z, xb.w};
    bf16x8 ah, al;
    #pragma unroll
    for (int j = 0; j < 8; ++j) {
      us hi = f2bf(xv[j]);
      ah[j] = (short)hi;
      al[j] = (short)f2bf(xv[j] - bf2f(hi));
    }
    #pragma unroll
    for (int nt = 0; nt < 3; ++nt) {
      bf16x8 bh = *(const bf16x8*)(&whi[(l31 + 32 * nt) * WP + d0]);
      bf16x8 bl = *(const bf16x8*)(&wlo[(l31 + 32 * nt) * WP + d0]);
      acc[nt] = mfma(ah, bh, acc[nt]);
      acc[nt] = mfma(al, bh, acc[nt]);
      acc[nt] = mfma(ah, bl, acc[nt]);
    }
  }
  __syncthreads();

  const float cq = 0.18033688011112042f;  // 0.125 * log2(e) folded into Q
  #pragma unroll
  for (int nt = 0; nt < 3; ++nt) {
    const bool isQ = (ch == 0) && (nt < 2);
    const int col = 32 * nt + l31;
    #pragma unroll
    for (int r = 0; r < 16; ++r) {
      const int rl = (r & 3) + 8 * (r >> 2) + 4 * h;
      float v = acc[nt][r];
      if (isQ) v *= cq;
      us hi = f2bf(v);
      us lo = f2bf(v - bf2f(hi));
      sm.ttile[(wid * 32 + rl) * TP + col] = (unsigned)hi | ((unsigned)lo << 16);
    }
  }
  __syncthreads();

  const int row = t >> 1;
  const int grow = rb * 128 + row;
  if (ch == 0) {
    {  // Q: local cols 0..63
      const int cb = (t & 1) * 32;
      unsigned hw[16], lw[16];
      #pragma unroll
      for (int j = 0; j < 16; ++j) {
        unsigned a = sm.ttile[row * TP + cb + 2 * j];
        unsigned bv = sm.ttile[row * TP + cb + 2 * j + 1];
        hw[j] = (a & 0xffffu) | (bv << 16);
        lw[j] = (a >> 16) | (bv & 0xffff0000u);
      }
      #pragma unroll
      for (int j = 0; j < 4; ++j) {
        uint4 hv = {hw[4 * j], hw[4 * j + 1], hw[4 * j + 2], hw[4 * j + 3]};
        uint4 lv = {lw[4 * j], lw[4 * j + 1], lw[4 * j + 2], lw[4 * j + 3]};
        *(uint4*)(Qhi + (size_t)grow * 64 + cb + 8 * j) = hv;
        *(uint4*)(Qlo + (size_t)grow * 64 + cb + 8 * j) = lv;
      }
    }
    {  // K: local cols 64..95 -> e 0..31
      const int cs = (t & 1) * 16;
      unsigned hw[8], lw[8];
      #pragma unroll
      for (int j = 0; j < 8; ++j) {
        unsigned a = sm.ttile[row * TP + 64 + cs + 2 * j];
        unsigned bv = sm.ttile[row * TP + 64 + cs + 2 * j + 1];
        hw[j] = (a & 0xffffu) | (bv << 16);
        lw[j] = (a >> 16) | (bv & 0xffff0000u);
      }
      #pragma unroll
      for (int j = 0; j < 2; ++j) {
        uint4 hv = {hw[4 * j], hw[4 * j + 1], hw[4 * j + 2], hw[4 * j + 3]};
        uint4 lv = {lw[4 * j], lw[4 * j + 1], lw[4 * j + 2], lw[4 * j + 3]};
        *(uint4*)(Khi + (size_t)grow * 64 + cs + 8 * j) = hv;
        *(uint4*)(Klo + (size_t)grow * 64 + cs + 8 * j) = lv;
      }
    }
  } else {
    {  // K: local cols 0..31 -> e 32..63
      const int cs = (t & 1) * 16;
      unsigned hw[8], lw[8];
      #pragma unroll
      for (int j = 0; j < 8; ++j) {
        unsigned a = sm.ttile[row * TP + cs + 2 * j];
        unsigned bv = sm.ttile[row * TP + cs + 2 * j + 1];
        hw[j] = (a & 0xffffu) | (bv << 16);
        lw[j] = (a >> 16) | (bv & 0xffff0000u);
      }
      #pragma unroll
      for (int j = 0; j < 2; ++j) {
        uint4 hv = {hw[4 * j], hw[4 * j + 1], hw[4 * j + 2], hw[4 * j + 3]};
        uint4 lv = {lw[4 * j], lw[4 * j + 1], lw[4 * j + 2], lw[4 * j + 3]};
        *(uint4*)(Khi + (size_t)grow * 64 + 32 + cs + 8 * j) = hv;
        *(uint4*)(Klo + (size_t)grow * 64 + 32 + cs + 8 * j) = lv;
      }
    }
    {  // V: local cols 32..95 -> Vt[b][e][n]
      const int bb = (rb * 128) >> 12;
      const int nb = (rb * 128) & 4095;
      #pragma unroll
      for (int i2 = 0; i2 < 4; ++i2) {
        const int c = t + 256 * i2;
        const int e = c >> 4, nc = c & 15;
        unsigned p[4];
        #pragma unroll
        for (int j = 0; j < 4; ++j) {
          unsigned a = sm.ttile[(nc * 8 + 2 * j) * TP + 32 + e];
          unsigned bv = sm.ttile[(nc * 8 + 2 * j + 1) * TP + 32 + e];
          p[j] = (a & 0xffffu) | (bv << 16);
        }
        uint4 pv = {p[0], p[1], p[2], p[3]};
        *(uint4*)(Vt + ((size_t)(bb * 64 + e) << 12) + nb + nc * 8) = pv;
      }
    }
  }
}

// ---------------------------------------------------------------------------
// Kernel 2: flash attention partials. 512 blocks x 256 thr (4 waves).
// Block = (batch, 256-q group, key-segment of 512). The 4 waves share each
// 64-key K/V tile (K logical traffic /4); each wave owns 64 q. Next tile
// prefetched into registers (6 x b128/thread) at iter top, staged to LDS
// behind a barrier at iter end -> global latency hidden by S+softmax+PV.
// LDS 65.5 KB -> 2 blocks/CU -> 2 waves/SIMD.
// ---------------------------------------------------------------------------
#define KP 72  // LDS pitch (shorts): conflict-free b128 frag reads

__global__ __launch_bounds__(256, 2) void attn_kernel(
    const us* __restrict__ Qhi, const us* __restrict__ Qlo,
    const us* __restrict__ Khi, const us* __restrict__ Klo,
    const us* __restrict__ Vt,
    us* __restrict__ Opart, float* __restrict__ Mpart,
    float* __restrict__ Lpart)
{
  __shared__ us bufK0[64 * KP];      // Khi tile
  __shared__ us bufK1[64 * KP];      // Klo tile
  __shared__ us bufV[64 * KP];       // V tile (Vt rows)
  __shared__ us bufP[4][64 * KP];    // per-wave P
  __shared__ float alds[4][64];

  // XCD-aware map: XCD x serves batch x>>1
  const int bx = blockIdx.x;
  const int xc = bx & 7, b = xc >> 1;
  const int idx = ((bx >> 3) << 1) | (xc & 1);  // 0..127
  const int seg = idx & 7, qg = idx >> 3;       // seg 0..7, qg 0..15
  const int t = threadIdx.x;
  const int wid = t >> 6, lane = t & 63;
  const int l31 = lane & 31, h = lane >> 5;
  const int qblk = qg * 4 + wid;                // 0..63
  const int qw = b * 64 + qblk;

  // persistent Q fragments: B-frag layout n=l31(+32qt), k=16*ks+8*h+j
  bf16x8 qh[2][4], ql[2][4];
  #pragma unroll
  for (int qt = 0; qt < 2; ++qt) {
    const size_t rg = (size_t)(b * 4096 + qblk * 64 + l31 + 32 * qt) * 64;
    #pragma unroll
    for (int ks = 0; ks < 4; ++ks) {
      qh[qt][ks] = *(const bf16x8*)(Qhi + rg + ks * 16 + h * 8);
      ql[qt][ks] = *(const bf16x8*)(Qlo + rg + ks * 16 + h * 8);
    }
  }
  const size_t kbase = (size_t)b * 262144;  // b*4096*64
  const size_t vbase = (size_t)b * 262144;  // b*64*4096

  // staging assignment: thread t covers chunks c = t, t+256 (row=c>>3, 16B col)
  const int c0 = t, c1 = t + 256;
  const int r0 = c0 >> 3, e0 = (c0 & 7) * 8;
  const int r1 = c1 >> 3, e1 = (c1 & 7) * 8;

  // prologue: load + stage tile 0
  const int key00 = seg * 512;
  bf16x8 pkh[2], pkl[2], pv[2];
  pkh[0] = *(const bf16x8*)(Khi + kbase + (size_t)(key00 + r0) * 64 + e0);
  pkh[1] = *(const bf16x8*)(Khi + kbase + (size_t)(key00 + r1) * 64 + e1);
  pkl[0] = *(const bf16x8*)(Klo + kbase + (size_t)(key00 + r0) * 64 + e0);
  pkl[1] = *(const bf16x8*)(Klo + kbase + (size_t)(key00 + r1) * 64 + e1);
  pv[0]  = *(const bf16x8*)(Vt + vbase + (size_t)r0 * 4096 + key00 + e0);
  pv[1]  = *(const bf16x8*)(Vt + vbase + (size_t)r1 * 4096 + key00 + e1);
  *(bf16x8*)(&bufK0[r0 * KP + e0]) = pkh[0];
  *(bf16x8*)(&bufK0[r1 * KP + e1]) = pkh[1];
  *(bf16x8*)(&bufK1[r0 * KP + e0]) = pkl[0];
  *(bf16x8*)(&bufK1[r1 * KP + e1]) = pkl[1];
  *(bf16x8*)(&bufV[r0 * KP + e0]) = pv[0];
  *(bf16x8*)(&bufV[r1 * KP + e1]) = pv[1];
  __syncthreads();

  f32x16 o[2][2] = {};
  float mrun[2] = {-__builtin_inff(), -__builtin_inff()};
  float lrun[2] = {0.f, 0.f};

  for (int it = 0; it < 8; ++it) {
    // prefetch next tile into regs (last iter: reload tile 7, unused)
    const int nk = seg * 512 + (it < 7 ? it + 1 : 7) * 64;
    pkh[0] = *(const bf16x8*)(Khi + kbase + (size_t)(nk + r0) * 64 + e0);
    pkh[1] = *(const bf16x8*)(Khi + kbase + (size_t)(nk + r1) * 64 + e1);
    pkl[0] = *(const bf16x8*)(Klo + kbase + (size_t)(nk + r0) * 64 + e0);
    pkl[1] = *(const bf16x8*)(Klo + kbase + (size_t)(nk + r1) * 64 + e1);
    pv[0]  = *(const bf16x8*)(Vt + vbase + (size_t)r0 * 4096 + nk + e0);
    pv[1]  = *(const bf16x8*)(Vt + vbase + (size_t)r1 * 4096 + nk + e1);

    // S^T = K_tile · Q'^T  (3-pass hi/lo)
    f32x16 s[2][2] = {};
    #pragma unroll
    for (int m = 0; m < 2; ++m) {
      #pragma unroll
      for (int ks = 0; ks < 4; ++ks) {
        const int off = (32 * m + l31) * KP + ks * 16 + h * 8;
        bf16x8 ah = *(const bf16x8*)(&bufK0[off]);
        bf16x8 al = *(const bf16x8*)(&bufK1[off]);
        #pragma unroll
        for (int qt = 0; qt < 2; ++qt) {
          s[m][qt] = mfma(ah, qh[qt][ks], s[m][qt]);
          s[m][qt] = mfma(al, qh[qt][ks], s[m][qt]);
          s[m][qt] = mfma(ah, ql[qt][ks], s[m][qt]);
        }
      }
    }

    // online softmax (base-2). Lane owns q=32qt+l31; partner (xor 32) holds
    // the other 32 key-scores.
    float alpha[2];
    #pragma unroll
    for (int qt = 0; qt < 2; ++qt) {
      float vm = -__builtin_inff();
      #pragma unroll
      for (int r = 0; r < 16; ++r)
        vm = fmaxf(vm, fmaxf(s[0][qt][r], s[1][qt][r]));
      vm = fmaxf(vm, __shfl_xor(vm, 32));
      const float mnew = fmaxf(mrun[qt], vm);
      alpha[qt] = EXP2(mrun[qt] - mnew);
      float sum = 0.f;
      #pragma unroll
      for (int r = 0; r < 16; ++r) {
        const float p0 = EXP2(s[0][qt][r] - mnew);
        const float p1 = EXP2(s[1][qt][r] - mnew);
        s[0][qt][r] = p0;
        s[1][qt][r] = p1;
        sum += p0 + p1;
      }
      sum += __shfl_xor(sum, 32);
      lrun[qt] = lrun[qt] * alpha[qt] + sum;
      mrun[qt] = mnew;
    }

    // write P into private bufP: row q=32qt+l31, 4 consecutive keys per pack
    us* myP = bufP[wid];
    #pragma unroll
    for (int qt = 0; qt < 2; ++qt) {
      #pragma unroll
      for (int m = 0; m < 2; ++m) {
        #pragma unroll
        for (int g = 0; g < 4; ++g) {
          uint2 u;
          u.x = pk2(s[m][qt][4 * g + 0], s[m][qt][4 * g + 1]);
          u.y = pk2(s[m][qt][4 * g + 2], s[m][qt][4 * g + 3]);
          *(uint2*)(&myP[(l31 + 32 * qt) * KP + 32 * m + 8 * g + 4 * h]) = u;
        }
      }
    }

    // rescale O by alpha (skip when all-ones)
    if (__any((alpha[0] != 1.f) || (alpha[1] != 1.f))) {
      alds[wid][lane] = h ? alpha[1] : alpha[0];
      #pragma unroll
      for (int qt = 0; qt < 2; ++qt) {
        #pragma unroll
        for (int g = 0; g < 4; ++g) {
          const float4 af = *(const float4*)(&alds[wid][32 * qt + 8 * g + 4 * h]);
          #pragma unroll
          for (int rr = 0; rr < 4; ++rr) {
            const int r = 4 * g + rr;
            const float a = (rr == 0) ? af.x : (rr == 1) ? af.y
                           : (rr == 2) ? af.z : af.w;
            o[qt][0][r] *= a;
            o[qt][1][r] *= a;
          }
        }
      }
    }

    // PV: O[q][d] += P[q][key] * V[key][d]
    #pragma unroll
    for (int ks = 0; ks < 4; ++ks) {
      const int fo = ks * 16 + h * 8;
      bf16x8 p0 = *(const bf16x8*)(&myP[l31 * KP + fo]);
      bf16x8 p1 = *(const bf16x8*)(&myP[(l31 + 32) * KP + fo]);
      bf16x8 w0 = *(const bf16x8*)(&bufV[l31 * KP + fo]);
      bf16x8 w1 = *(const bf16x8*)(&bufV[(l31 + 32) * KP + fo]);
      o[0][0] = mfma(p0, w0, o[0][0]);
      o[0][1] = mfma(p0, w1, o[0][1]);
      o[1][0] = mfma(p1, w0, o[1][0]);
      o[1][1] = mfma(p1, w1, o[1][1]);
    }

    // stage prefetched tile (barrier: everyone done reading bufK/bufV)
    __syncthreads();
    *(bf16x8*)(&bufK0[r0 * KP + e0]) = pkh[0];
    *(bf16x8*)(&bufK0[r1 * KP + e1]) = pkh[1];
    *(bf16x8*)(&bufK1[r0 * KP + e0]) = pkl[0];
    *(bf16x8*)(&bufK1[r1 * KP + e1]) = pkl[1];
    *(bf16x8*)(&bufV[r0 * KP + e0]) = pv[0];
    *(bf16x8*)(&bufV[r1 * KP + e1]) = pv[1];
    __syncthreads();
  }

  // epilogue: O -> bf16 Opart via LDS bounce, fully dwordx4-coalesced.
  // (round-2 lesson: 2B scalar global stores amplify writes ~6x)
  const size_t pb = (size_t)(qw * 8 + seg);
  float* fb = (float*)bufP[wid];              // 2304 floats avail, need 2112
  #pragma unroll
  for (int qt = 0; qt < 2; ++qt) {
    // write o (fp32, pitch 66) — wave-private, in-order DS, no barrier
    #pragma unroll
    for (int dt = 0; dt < 2; ++dt) {
      #pragma unroll
      for (int r = 0; r < 16; ++r) {
        const int qrow = (r & 3) + 8 * (r >> 2) + 4 * h;  // 0..31
        fb[qrow * 66 + l31 + 32 * dt] = o[qt][dt][r];
      }
    }
    // read back packed: lane covers 4 chunks of 8 d (16B out each)
    #pragma unroll
    for (int jj = 0; jj < 4; ++jj) {
      const int chunk = lane + 64 * jj;       // 0..255
      const int row = chunk >> 3, part = chunk & 7;
      const float* src = &fb[row * 66 + part * 8];
      float2 a0 = *(const float2*)(src + 0);
      float2 a1 = *(const float2*)(src + 2);
      float2 a2 = *(const float2*)(src + 4);
      float2 a3 = *(const float2*)(src + 6);
      uint4 pkv;
      pkv.x = pk2(a0.x, a0.y);
      pkv.y = pk2(a1.x, a1.y);
      pkv.z = pk2(a2.x, a2.y);
      pkv.w = pk2(a3.x, a3.y);
      *(uint4*)(Opart + pb * 4096 + (size_t)(32 * qt + row) * 64 + part * 8) = pkv;
    }
  }
  Mpart[pb * 64 + lane] = h ? mrun[1] : mrun[0];
  Lpart[pb * 64 + lane] = h ? lrun[1] : lrun[0];
}

// ---------------------------------------------------------------------------
// Kernel 3: merge 8 key-segment partials (bf16). 131072 threads, 8 d each.
// ---------------------------------------------------------------------------
__global__ __launch_bounds__(256, 1) void merge_kernel(
    const us* __restrict__ Opart, const float* __restrict__ Mpart,
    const float* __restrict__ Lpart, float* __restrict__ out)
{
  const int tg = blockIdx.x * 256 + threadIdx.x;
  const int q = tg >> 3, dc = (tg & 7) * 8;
  const int qw = q >> 6, ql = q & 63;
  const int base = qw * 8;
  float m[8];
  float M = -__builtin_inff();
  #pragma unroll
  for (int s = 0; s < 8; ++s) {
    m[s] = Mpart[(size_t)(base + s) * 64 + ql];
    M = fmaxf(M, m[s]);
  }
  float acc[8] = {};
  float den = 0.f;
  #pragma unroll
  for (int s = 0; s < 8; ++s) {
    const float wgt = EXP2(m[s] - M);
    den += wgt * Lpart[(size_t)(base + s) * 64 + ql];
    const uint4 r = *(const uint4*)(Opart + (size_t)(base + s) * 4096 +
                                    ql * 64 + dc);
    const unsigned rw[4] = {r.x, r.y, r.z, r.w};
    #pragma unroll
    for (int j = 0; j < 4; ++j) {
      acc[2 * j]     += wgt * bf2f((us)(rw[j] & 0xffffu));
      acc[2 * j + 1] += wgt * bf2f((us)(rw[j] >> 16));
    }
  }
  const float inv = 1.f / den;
  float4 r0 = {acc[0] * inv, acc[1] * inv, acc[2] * inv, acc[3] * inv};
  float4 r1 = {acc[4] * inv, acc[5] * inv, acc[6] * inv, acc[7] * inv};
  *(float4*)(out + (size_t)q * 64 + dc) = r0;
  *(float4*)(out + (size_t)q * 64 + dc + 4) = r1;
}

// ---------------------------------------------------------------------------
extern "C" void kernel_launch(void* const* d_in, const int* in_sizes, int n_in,
                              void* d_out, int out_size, void* d_ws,
                              size_t ws_size, hipStream_t stream)
{
  const float* x = (const float*)d_in[0];
  const float* w = (const float*)d_in[1];
  float* out = (float*)d_out;
  char* ws = (char*)d_ws;

  const size_t T = 2097152;  // bytes per bf16 [4,4096,64] tensor
  us* Qhi = (us*)(ws + 0 * T);
  us* Qlo = (us*)(ws + 1 * T);
  us* Khi = (us*)(ws + 2 * T);
  us* Klo = (us*)(ws + 3 * T);
  us* Vt  = (us*)(ws + 4 * T);
  us* Opart = (us*)(ws + 5 * T);                             // 16,777,216 B
  float* Mpart = (float*)(ws + 5 * T + 16777216);            //    524,288 B
  float* Lpart = (float*)(ws + 5 * T + 16777216 + 524288);   //    524,288 B
  // total workspace use: ~28.3 MiB

  hipLaunchKernelGGL(qkv_kernel, dim3(256), dim3(256), 0, stream,
                     x, w, Qhi, Qlo, Khi, Klo, Vt);
  hipLaunchKernelGGL(attn_kernel, dim3(512), dim3(256), 0, stream,
                     Qhi, Qlo, Khi, Klo, Vt, Opart, Mpart, Lpart);
  hipLaunchKernelGGL(merge_kernel, dim3(512), dim3(256), 0, stream,
                     Opart, Mpart, Lpart, out);
}

// Round 4
// 149.036 us; speedup vs baseline: 1.2465x; 1.0032x over previous
//
#include <hip/hip_runtime.h>

// ---------------------------------------------------------------------------
// Self-attention: out = softmax((xWq)(xWk)^T / sqrt(64)) (xWv)
// B=4, N=4096, Din=128, Dout=64.
//   k1 qkv_kernel : x@W via 3-pass bf16 MFMA -> Qhi/Qlo (pre-scaled), Khi/Klo,
//                   Vt [b][d][n] bf16. Epilogue via LDS transpose, coalesced.
//   k2 attn_kernel: flash attention, 256-thr blocks (4 waves share K/V tiles),
//                   DOUBLE-BUFFERED tiles (1 barrier/iter), XOR-swizzled LDS
//                   (conflict-free, no pitch padding), P converted C->A layout
//                   in registers via shfl_xor(32) (no P LDS round-trip).
//   k3 merge_kernel: combine 8 segment partials (bf16 O partials).
// ---------------------------------------------------------------------------

typedef __attribute__((ext_vector_type(8))) short bf16x8;
typedef __attribute__((ext_vector_type(16))) float f32x16;
typedef __attribute__((ext_vector_type(4))) unsigned u32x4;
typedef unsigned short us;

__device__ __forceinline__ us f2bf(float f) {               // RTNE fp32->bf16
  unsigned u = __builtin_bit_cast(unsigned, f);
  u += 0x7FFFu + ((u >> 16) & 1u);
  return (us)(u >> 16);
}
__device__ __forceinline__ float bf2f(us h) {
  unsigned u = ((unsigned)h) << 16;
  return __builtin_bit_cast(float, u);
}
__device__ __forceinline__ f32x16 mfma(bf16x8 a, bf16x8 b, f32x16 c) {
  return __builtin_amdgcn_mfma_f32_32x32x16_bf16(a, b, c, 0, 0, 0);
}
__device__ __forceinline__ unsigned pk2(float a, float b) {
  return (unsigned)f2bf(a) | ((unsigned)f2bf(b) << 16);
}
#define EXP2(x) __builtin_amdgcn_exp2f(x)

// ---------------------------------------------------------------------------
// Kernel 1: QKV projection (unchanged; passed rounds 2-3).
// ---------------------------------------------------------------------------
#define WP 136  // W tile pitch (shorts)
#define TP 101  // transpose tile pitch (uints)

__global__ __launch_bounds__(256, 1) void qkv_kernel(
    const float* __restrict__ x, const float* __restrict__ w,
    us* __restrict__ Qhi, us* __restrict__ Qlo,
    us* __restrict__ Khi, us* __restrict__ Klo, us* __restrict__ Vt)
{
  __shared__ union {
    us wtile[2][96 * WP];
    unsigned ttile[128 * TP];
  } sm;
  us* whi = sm.wtile[0];
  us* wlo = sm.wtile[1];
  const int t = threadIdx.x;
  const int rb = blockIdx.x >> 1, ch = blockIdx.x & 1;

  for (int i = t; i < 24576; i += 256) {
    int p = i >> 13, rem = i & 8191;
    int d = rem >> 6, e = rem & 63;
    int cl = ((p << 6) + e) - ch * 96;
    if ((unsigned)cl < 96u) {
      float v = w[i];
      us hi = f2bf(v);
      whi[cl * WP + d] = hi;
      wlo[cl * WP + d] = f2bf(v - bf2f(hi));
    }
  }
  __syncthreads();

  const int wid = t >> 6, lane = t & 63;
  const int l31 = lane & 31, h = lane >> 5;
  const int rbase = rb * 128 + wid * 32;
  const float* xrow = x + (size_t)(rbase + l31) * 128;

  f32x16 acc[3] = {};
  #pragma unroll
  for (int ks = 0; ks < 8; ++ks) {
    const int d0 = ks * 16 + h * 8;
    const float4 xa = *(const float4*)(xrow + d0);
    const float4 xb = *(const float4*)(xrow + d0 + 4);
    const float xv[8] = {xa.x, xa.y, xa.z, xa.w, xb.x, xb.y, xb.z, xb.w};
    bf16x8 ah, al;
    #pragma unroll
    for (int j = 0; j < 8; ++j) {
      us hi = f2bf(xv[j]);
      ah[j] = (short)hi;
      al[j] = (short)f2bf(xv[j] - bf2f(hi));
    }
    #pragma unroll
    for (int nt = 0; nt < 3; ++nt) {
      bf16x8 bh = *(const bf16x8*)(&whi[(l31 + 32 * nt) * WP + d0]);
      bf16x8 bl = *(const bf16x8*)(&wlo[(l31 + 32 * nt) * WP + d0]);
      acc[nt] = mfma(ah, bh, acc[nt]);
      acc[nt] = mfma(al, bh, acc[nt]);
      acc[nt] = mfma(ah, bl, acc[nt]);
    }
  }
  __syncthreads();

  const float cq = 0.18033688011112042f;  // 0.125 * log2(e) folded into Q
  #pragma unroll
  for (int nt = 0; nt < 3; ++nt) {
    const bool isQ = (ch == 0) && (nt < 2);
    const int col = 32 * nt + l31;
    #pragma unroll
    for (int r = 0; r < 16; ++r) {
      const int rl = (r & 3) + 8 * (r >> 2) + 4 * h;
      float v = acc[nt][r];
      if (isQ) v *= cq;
      us hi = f2bf(v);
      us lo = f2bf(v - bf2f(hi));
      sm.ttile[(wid * 32 + rl) * TP + col] = (unsigned)hi | ((unsigned)lo << 16);
    }
  }
  __syncthreads();

  const int row = t >> 1;
  const int grow = rb * 128 + row;
  if (ch == 0) {
    {  // Q: local cols 0..63
      const int cb = (t & 1) * 32;
      unsigned hw[16], lw[16];
      #pragma unroll
      for (int j = 0; j < 16; ++j) {
        unsigned a = sm.ttile[row * TP + cb + 2 * j];
        unsigned bv = sm.ttile[row * TP + cb + 2 * j + 1];
        hw[j] = (a & 0xffffu) | (bv << 16);
        lw[j] = (a >> 16) | (bv & 0xffff0000u);
      }
      #pragma unroll
      for (int j = 0; j < 4; ++j) {
        uint4 hv = {hw[4 * j], hw[4 * j + 1], hw[4 * j + 2], hw[4 * j + 3]};
        uint4 lv = {lw[4 * j], lw[4 * j + 1], lw[4 * j + 2], lw[4 * j + 3]};
        *(uint4*)(Qhi + (size_t)grow * 64 + cb + 8 * j) = hv;
        *(uint4*)(Qlo + (size_t)grow * 64 + cb + 8 * j) = lv;
      }
    }
    {  // K: local cols 64..95 -> e 0..31
      const int cs = (t & 1) * 16;
      unsigned hw[8], lw[8];
      #pragma unroll
      for (int j = 0; j < 8; ++j) {
        unsigned a = sm.ttile[row * TP + 64 + cs + 2 * j];
        unsigned bv = sm.ttile[row * TP + 64 + cs + 2 * j + 1];
        hw[j] = (a & 0xffffu) | (bv << 16);
        lw[j] = (a >> 16) | (bv & 0xffff0000u);
      }
      #pragma unroll
      for (int j = 0; j < 2; ++j) {
        uint4 hv = {hw[4 * j], hw[4 * j + 1], hw[4 * j + 2], hw[4 * j + 3]};
        uint4 lv = {lw[4 * j], lw[4 * j + 1], lw[4 * j + 2], lw[4 * j + 3]};
        *(uint4*)(Khi + (size_t)grow * 64 + cs + 8 * j) = hv;
        *(uint4*)(Klo + (size_t)grow * 64 + cs + 8 * j) = lv;
      }
    }
  } else {
    {  // K: local cols 0..31 -> e 32..63
      const int cs = (t & 1) * 16;
      unsigned hw[8], lw[8];
      #pragma unroll
      for (int j = 0; j < 8; ++j) {
        unsigned a = sm.ttile[row * TP + cs + 2 * j];
        unsigned bv = sm.ttile[row * TP + cs + 2 * j + 1];
        hw[j] = (a & 0xffffu) | (bv << 16);
        lw[j] = (a >> 16) | (bv & 0xffff0000u);
      }
      #pragma unroll
      for (int j = 0; j < 2; ++j) {
        uint4 hv = {hw[4 * j], hw[4 * j + 1], hw[4 * j + 2], hw[4 * j + 3]};
        uint4 lv = {lw[4 * j], lw[4 * j + 1], lw[4 * j + 2], lw[4 * j + 3]};
        *(uint4*)(Khi + (size_t)grow * 64 + 32 + cs + 8 * j) = hv;
        *(uint4*)(Klo + (size_t)grow * 64 + 32 + cs + 8 * j) = lv;
      }
    }
    {  // V: local cols 32..95 -> Vt[b][e][n]
      const int bb = (rb * 128) >> 12;
      const int nb = (rb * 128) & 4095;
      #pragma unroll
      for (int i2 = 0; i2 < 4; ++i2) {
        const int c = t + 256 * i2;
        const int e = c >> 4, nc = c & 15;
        unsigned p[4];
        #pragma unroll
        for (int j = 0; j < 4; ++j) {
          unsigned a = sm.ttile[(nc * 8 + 2 * j) * TP + 32 + e];
          unsigned bv = sm.ttile[(nc * 8 + 2 * j + 1) * TP + 32 + e];
          p[j] = (a & 0xffffu) | (bv << 16);
        }
        uint4 pv = {p[0], p[1], p[2], p[3]};
        *(uint4*)(Vt + ((size_t)(bb * 64 + e) << 12) + nb + nc * 8) = pv;
      }
    }
  }
}

// ---------------------------------------------------------------------------
// Kernel 2: flash attention partials. 512 blocks x 256 thr (4 waves).
// Double-buffered XOR-swizzled K/V tiles; single barrier per iter; P
// converted to A-layout via shfl_xor(32) pair exchange (no LDS round-trip).
// LDS layout: row stride 64 us (128B); 16B chunk at slot s holds data chunk
// s^(row&7)  -> staging writes and frag reads both conflict-free.
// ---------------------------------------------------------------------------
__global__ __launch_bounds__(256, 2) void attn_kernel(
    const us* __restrict__ Qhi, const us* __restrict__ Qlo,
    const us* __restrict__ Khi, const us* __restrict__ Klo,
    const us* __restrict__ Vt,
    us* __restrict__ Opart, float* __restrict__ Mpart,
    float* __restrict__ Lpart)
{
  __shared__ us sKh[2][64 * 64];   // Khi tiles (double buffer)
  __shared__ us sKl[2][64 * 64];   // Klo tiles
  __shared__ us sV[2][64 * 64];    // V tiles
  __shared__ float alds[4][64];

  // XCD-aware map: XCD x serves batch x>>1
  const int bx = blockIdx.x;
  const int xc = bx & 7, b = xc >> 1;
  const int idx = ((bx >> 3) << 1) | (xc & 1);  // 0..127
  const int seg = idx & 7, qg = idx >> 3;       // seg 0..7, qg 0..15
  const int t = threadIdx.x;
  const int wid = t >> 6, lane = t & 63;
  const int l31 = lane & 31, h = lane >> 5;
  const int qblk = qg * 4 + wid;                // 0..63
  const int qw = b * 64 + qblk;

  // persistent Q fragments: B-frag layout n=l31(+32qt), k=16*ks+8*h+j
  bf16x8 qh[2][4], ql[2][4];
  #pragma unroll
  for (int qt = 0; qt < 2; ++qt) {
    const size_t rg = (size_t)(b * 4096 + qblk * 64 + l31 + 32 * qt) * 64;
    #pragma unroll
    for (int ks = 0; ks < 4; ++ks) {
      qh[qt][ks] = *(const bf16x8*)(Qhi + rg + ks * 16 + h * 8);
      ql[qt][ks] = *(const bf16x8*)(Qlo + rg + ks * 16 + h * 8);
    }
  }
  const size_t kbase = (size_t)b * 262144;  // b*4096*64
  const size_t vbase = (size_t)b * 262144;  // b*64*4096

  // staging: thread t covers (row0, slot) and (row0+32, slot)
  const int row0 = t >> 3, slot = t & 7;
  const int gcol = (slot ^ (row0 & 7)) * 8;   // same for row0+32
  const int ld0 = row0 * 64 + slot * 8;       // LDS us-offset row0
  const int ld1 = ld0 + 32 * 64;              // row0+32

  // prologue: tile 0 -> buffer 0
  {
    const int k0 = seg * 512;
    *(bf16x8*)(&sKh[0][ld0]) = *(const bf16x8*)(Khi + kbase + (size_t)(k0 + row0) * 64 + gcol);
    *(bf16x8*)(&sKh[0][ld1]) = *(const bf16x8*)(Khi + kbase + (size_t)(k0 + row0 + 32) * 64 + gcol);
    *(bf16x8*)(&sKl[0][ld0]) = *(const bf16x8*)(Klo + kbase + (size_t)(k0 + row0) * 64 + gcol);
    *(bf16x8*)(&sKl[0][ld1]) = *(const bf16x8*)(Klo + kbase + (size_t)(k0 + row0 + 32) * 64 + gcol);
    *(bf16x8*)(&sV[0][ld0])  = *(const bf16x8*)(Vt + vbase + (size_t)row0 * 4096 + k0 + gcol);
    *(bf16x8*)(&sV[0][ld1])  = *(const bf16x8*)(Vt + vbase + (size_t)(row0 + 32) * 4096 + k0 + gcol);
  }
  __syncthreads();

  f32x16 o[2][2] = {};
  float mrun[2] = {-__builtin_inff(), -__builtin_inff()};
  float lrun[2] = {0.f, 0.f};

  for (int it = 0; it < 8; ++it) {
    const int cur = it & 1, nxt = cur ^ 1;

    // prefetch next tile into regs (issued before compute; staged after S)
    bf16x8 nk0, nk1, nl0, nl1, nv0, nv1;
    if (it < 7) {
      const int nk = seg * 512 + (it + 1) * 64;
      nk0 = *(const bf16x8*)(Khi + kbase + (size_t)(nk + row0) * 64 + gcol);
      nk1 = *(const bf16x8*)(Khi + kbase + (size_t)(nk + row0 + 32) * 64 + gcol);
      nl0 = *(const bf16x8*)(Klo + kbase + (size_t)(nk + row0) * 64 + gcol);
      nl1 = *(const bf16x8*)(Klo + kbase + (size_t)(nk + row0 + 32) * 64 + gcol);
      nv0 = *(const bf16x8*)(Vt + vbase + (size_t)row0 * 4096 + nk + gcol);
      nv1 = *(const bf16x8*)(Vt + vbase + (size_t)(row0 + 32) * 4096 + nk + gcol);
    }

    // S^T = K_tile · Q'^T  (3-pass hi/lo); swizzled frag reads
    f32x16 s[2][2] = {};
    #pragma unroll
    for (int m = 0; m < 2; ++m) {
      const int krow = 32 * m + l31;
      #pragma unroll
      for (int ks = 0; ks < 4; ++ks) {
        const int off = krow * 64 + (((2 * ks + h) ^ (l31 & 7)) * 8);
        bf16x8 ah = *(const bf16x8*)(&sKh[cur][off]);
        bf16x8 al = *(const bf16x8*)(&sKl[cur][off]);
        #pragma unroll
        for (int qt = 0; qt < 2; ++qt) {
          s[m][qt] = mfma(ah, qh[qt][ks], s[m][qt]);
          s[m][qt] = mfma(al, qh[qt][ks], s[m][qt]);
          s[m][qt] = mfma(ah, ql[qt][ks], s[m][qt]);
        }
      }
    }

    // stage prefetched tile into the other buffer (no reader until barrier)
    if (it < 7) {
      *(bf16x8*)(&sKh[nxt][ld0]) = nk0;
      *(bf16x8*)(&sKh[nxt][ld1]) = nk1;
      *(bf16x8*)(&sKl[nxt][ld0]) = nl0;
      *(bf16x8*)(&sKl[nxt][ld1]) = nl1;
      *(bf16x8*)(&sV[nxt][ld0])  = nv0;
      *(bf16x8*)(&sV[nxt][ld1])  = nv1;
    }

    // online softmax (base-2) + pack P pairs (bf16) for the reg exchange.
    // pp[m][qt][p] packs regs (2p,2p+1) of s[m][qt].
    float alpha[2];
    unsigned pp[2][2][8];
    #pragma unroll
    for (int qt = 0; qt < 2; ++qt) {
      float vm = -__builtin_inff();
      #pragma unroll
      for (int r = 0; r < 16; ++r)
        vm = fmaxf(vm, fmaxf(s[0][qt][r], s[1][qt][r]));
      vm = fmaxf(vm, __shfl_xor(vm, 32));
      const float mnew = fmaxf(mrun[qt], vm);
      alpha[qt] = EXP2(mrun[qt] - mnew);
      float sum = 0.f;
      #pragma unroll
      for (int m = 0; m < 2; ++m) {
        #pragma unroll
        for (int p = 0; p < 8; ++p) {
          const float p0 = EXP2(s[m][qt][2 * p] - mnew);
          const float p1 = EXP2(s[m][qt][2 * p + 1] - mnew);
          sum += p0 + p1;
          pp[m][qt][p] = pk2(p0, p1);
        }
      }
      sum += __shfl_xor(sum, 32);
      lrun[qt] = lrun[qt] * alpha[qt] + sum;
      mrun[qt] = mnew;
    }

    // rescale O by alpha (LDS broadcast to C-layout rows)
    if (__any((alpha[0] != 1.f) || (alpha[1] != 1.f))) {
      alds[wid][lane] = h ? alpha[1] : alpha[0];
      #pragma unroll
      for (int qt = 0; qt < 2; ++qt) {
        #pragma unroll
        for (int g = 0; g < 4; ++g) {
          const float4 af = *(const float4*)(&alds[wid][32 * qt + 8 * g + 4 * h]);
          #pragma unroll
          for (int rr = 0; rr < 4; ++rr) {
            const int r = 4 * g + rr;
            const float a = (rr == 0) ? af.x : (rr == 1) ? af.y
                           : (rr == 2) ? af.z : af.w;
            o[qt][0][r] *= a;
            o[qt][1][r] *= a;
          }
        }
      }
    }

    // PV: build P A-frags via shfl_xor(32) pair exchange, V frags from LDS.
    // For chunk ks (keys 16ks..16ks+15): lane needs keys 16ks+8h+j.
    // own pairs = pp[m][qt][4(ks&1)+2h+{0,1}]; partner's complement arrives
    // via shfl_xor of (h ? pairs {0,1} : pairs {2,3}).
    #pragma unroll
    for (int ks = 0; ks < 4; ++ks) {
      const int m = ks >> 1, base = 4 * (ks & 1);
      bf16x8 af[2];
      #pragma unroll
      for (int qt = 0; qt < 2; ++qt) {
        const unsigned x0 = pp[m][qt][base + 0], x1 = pp[m][qt][base + 1];
        const unsigned x2 = pp[m][qt][base + 2], x3 = pp[m][qt][base + 3];
        const unsigned sA = h ? x0 : x2;
        const unsigned sB = h ? x1 : x3;
        const unsigned rA = (unsigned)__shfl_xor((int)sA, 32);
        const unsigned rB = (unsigned)__shfl_xor((int)sB, 32);
        u32x4 wv;
        wv.x = h ? rA : x0;
        wv.y = h ? rB : x1;
        wv.z = h ? x2 : rA;
        wv.w = h ? x3 : rB;
        af[qt] = __builtin_bit_cast(bf16x8, wv);
      }
      bf16x8 vf[2];
      #pragma unroll
      for (int dt = 0; dt < 2; ++dt) {
        const int vrow = l31 + 32 * dt;
        vf[dt] = *(const bf16x8*)(&sV[cur][vrow * 64 +
                                           (((2 * ks + h) ^ (l31 & 7)) * 8)]);
      }
      o[0][0] = mfma(af[0], vf[0], o[0][0]);
      o[0][1] = mfma(af[0], vf[1], o[0][1]);
      o[1][0] = mfma(af[1], vf[0], o[1][0]);
      o[1][1] = mfma(af[1], vf[1], o[1][1]);
    }

    __syncthreads();  // cur reads done; nxt writes visible
  }

  // epilogue: O -> bf16 Opart via LDS bounce (buffers dead), dwordx4 stores.
  const size_t pb = (size_t)(qw * 8 + seg);
  float* fb = (float*)(&sKh[0][0]) + wid * 2176;  // 4 x 2112 floats used
  #pragma unroll
  for (int qt = 0; qt < 2; ++qt) {
    #pragma unroll
    for (int dt = 0; dt < 2; ++dt) {
      #pragma unroll
      for (int r = 0; r < 16; ++r) {
        const int qrow = (r & 3) + 8 * (r >> 2) + 4 * h;  // 0..31
        fb[qrow * 66 + l31 + 32 * dt] = o[qt][dt][r];
      }
    }
    #pragma unroll
    for (int jj = 0; jj < 4; ++jj) {
      const int chunk = lane + 64 * jj;       // 0..255
      const int row = chunk >> 3, part = chunk & 7;
      const float* src = &fb[row * 66 + part * 8];
      float2 a0 = *(const float2*)(src + 0);
      float2 a1 = *(const float2*)(src + 2);
      float2 a2 = *(const float2*)(src + 4);
      float2 a3 = *(const float2*)(src + 6);
      uint4 pkv;
      pkv.x = pk2(a0.x, a0.y);
      pkv.y = pk2(a1.x, a1.y);
      pkv.z = pk2(a2.x, a2.y);
      pkv.w = pk2(a3.x, a3.y);
      *(uint4*)(Opart + pb * 4096 + (size_t)(32 * qt + row) * 64 + part * 8) = pkv;
    }
  }
  Mpart[pb * 64 + lane] = h ? mrun[1] : mrun[0];
  Lpart[pb * 64 + lane] = h ? lrun[1] : lrun[0];
}

// ---------------------------------------------------------------------------
// Kernel 3: merge 8 key-segment partials (bf16). 131072 threads, 8 d each.
// ---------------------------------------------------------------------------
__global__ __launch_bounds__(256, 1) void merge_kernel(
    const us* __restrict__ Opart, const float* __restrict__ Mpart,
    const float* __restrict__ Lpart, float* __restrict__ out)
{
  const int tg = blockIdx.x * 256 + threadIdx.x;
  const int q = tg >> 3, dc = (tg & 7) * 8;
  const int qw = q >> 6, ql = q & 63;
  const int base = qw * 8;
  float m[8];
  float M = -__builtin_inff();
  #pragma unroll
  for (int s = 0; s < 8; ++s) {
    m[s] = Mpart[(size_t)(base + s) * 64 + ql];
    M = fmaxf(M, m[s]);
  }
  float acc[8] = {};
  float den = 0.f;
  #pragma unroll
  for (int s = 0; s < 8; ++s) {
    const float wgt = EXP2(m[s] - M);
    den += wgt * Lpart[(size_t)(base + s) * 64 + ql];
    const uint4 r = *(const uint4*)(Opart + (size_t)(base + s) * 4096 +
                                    ql * 64 + dc);
    const unsigned rw[4] = {r.x, r.y, r.z, r.w};
    #pragma unroll
    for (int j = 0; j < 4; ++j) {
      acc[2 * j]     += wgt * bf2f((us)(rw[j] & 0xffffu));
      acc[2 * j + 1] += wgt * bf2f((us)(rw[j] >> 16));
    }
  }
  const float inv = 1.f / den;
  float4 r0 = {acc[0] * inv, acc[1] * inv, acc[2] * inv, acc[3] * inv};
  float4 r1 = {acc[4] * inv, acc[5] * inv, acc[6] * inv, acc[7] * inv};
  *(float4*)(out + (size_t)q * 64 + dc) = r0;
  *(float4*)(out + (size_t)q * 64 + dc + 4) = r1;
}

// ---------------------------------------------------------------------------
extern "C" void kernel_launch(void* const* d_in, const int* in_sizes, int n_in,
                              void* d_out, int out_size, void* d_ws,
                              size_t ws_size, hipStream_t stream)
{
  const float* x = (const float*)d_in[0];
  const float* w = (const float*)d_in[1];
  float* out = (float*)d_out;
  char* ws = (char*)d_ws;

  const size_t T = 2097152;  // bytes per bf16 [4,4096,64] tensor
  us* Qhi = (us*)(ws + 0 * T);
  us* Qlo = (us*)(ws + 1 * T);
  us* Khi = (us*)(ws + 2 * T);
  us* Klo = (us*)(ws + 3 * T);
  us* Vt  = (us*)(ws + 4 * T);
  us* Opart = (us*)(ws + 5 * T);                             // 16,777,216 B
  float* Mpart = (float*)(ws + 5 * T + 16777216);            //    524,288 B
  float* Lpart = (float*)(ws + 5 * T + 16777216 + 524288);   //    524,288 B
  // total workspace use: ~28.3 MiB

  hipLaunchKernelGGL(qkv_kernel, dim3(256), dim3(256), 0, stream,
                     x, w, Qhi, Qlo, Khi, Klo, Vt);
  hipLaunchKernelGGL(attn_kernel, dim3(512), dim3(256), 0, stream,
                     Qhi, Qlo, Khi, Klo, Vt, Opart, Mpart, Lpart);
  hipLaunchKernelGGL(merge_kernel, dim3(512), dim3(256), 0, stream,
                     Opart, Mpart, Lpart, out);
}